// Round 3
// baseline (360.324 us; speedup 1.0000x reference)
//
#include <hip/hip_runtime.h>

// SelfAttention block, fully restructured:
//   RS/SQ    : per-channel raw sums (stats_part_k)
//   prep     : group stats -> sc/sh, svec, rall
//   Graw     : x @ x^T per batch, f16 MFMA (raw x; GN affine folded later)
//   fused_logits: T1=Wq@G(affine on the fly), L=T1@Wk^T +corr, softmax, A^T, cv
//   fused_s  : T2=Pw@A, S=T2@Wv -> f16, const[b,o]
//   final    : out = x + S@xn + const  (f16 MFMA)

#define B_ 32
#define C_ 256
#define N_ 4096
#define GSIZE (32 * N_)
#define EPSV 1e-5f
#define SCALE 0.0625f

// workspace layout (float units)
#define OFF_SC    0
#define OFF_SH    8192
#define OFF_RS    16384
#define OFF_SQ    24576
#define OFF_RALL  32768
#define OFF_CV    57344
#define OFF_CONST 65536
#define OFF_WVT   73728                 // f16 [256][256] = 32768 floats
#define OFF_GM    106496                // 32 * 65536
#define OFF_AT    (OFF_GM + 2097152)    // A^T fp32 [b][j][r]
#define OFF_S16   (OFF_AT + 2097152)    // f16 [b][o][c]

typedef _Float16 half_t;
typedef half_t f16x8 __attribute__((ext_vector_type(8)));
typedef float f32x16 __attribute__((ext_vector_type(16)));

// ---------------- per-channel raw sums --------------------------------------
__global__ __launch_bounds__(256) void stats_part_k(const float* __restrict__ x,
                                                    float* __restrict__ ws) {
  int bid = blockIdx.x, b = bid >> 5, cb = bid & 31;
  int t = threadIdx.x, lane = t & 63, w = t >> 6;
#pragma unroll
  for (int i = 0; i < 2; ++i) {
    int c = cb * 8 + w * 2 + i;
    const float4* p = (const float4*)(x + ((size_t)b * C_ + c) * N_);
    float s = 0.f, q = 0.f;
#pragma unroll
    for (int j = 0; j < 16; ++j) {
      float4 v = p[lane + j * 64];
      s += v.x + v.y + v.z + v.w;
      q += v.x * v.x + v.y * v.y + v.z * v.z + v.w * v.w;
    }
#pragma unroll
    for (int off = 32; off > 0; off >>= 1) {
      s += __shfl_down(s, off);
      q += __shfl_down(q, off);
    }
    if (lane == 0) {
      ws[OFF_RS + b * 256 + c] = s;
      ws[OFF_SQ + b * 256 + c] = q;
    }
  }
}

// ---------------- prep: stats -> sc/sh, svec, rall --------------------------
__global__ __launch_bounds__(256) void prep_k(const float* __restrict__ gw,
                                              const float* __restrict__ gb,
                                              const float* __restrict__ qkvw,
                                              float* __restrict__ ws) {
  int b = blockIdx.x, t = threadIdx.x;
  __shared__ float sL[256], qL[256], svecs[256], gmean[8], grstd[8];
  float s = ws[OFF_RS + b * 256 + t], q = ws[OFF_SQ + b * 256 + t];
  sL[t] = s; qL[t] = q;
  __syncthreads();
  if (t < 8) {
    float gs = 0.f, gq = 0.f;
    for (int i = 0; i < 32; ++i) { gs += sL[t * 32 + i]; gq += qL[t * 32 + i]; }
    float mean = gs * (1.f / GSIZE);
    float var = gq * (1.f / GSIZE) - mean * mean;
    gmean[t] = mean;
    grstd[t] = rsqrtf(var + EPSV);
  }
  __syncthreads();
  int g = t >> 5;
  float sc = grstd[g] * gw[t];
  float sh = gb[t] - gmean[g] * sc;
  ws[OFF_SC + b * 256 + t] = sc;
  ws[OFF_SH + b * 256 + t] = sh;
  float sv = s * sc + 4096.f * sh;
  svecs[t] = sv;
  __syncthreads();
  for (int oo = 0; oo < 3; ++oo) {
    int o = t + oo * 256;
    const float* wr = qkvw + (size_t)o * 256;
    float acc = 0.f;
#pragma unroll 8
    for (int c = 0; c < 256; ++c) acc += wr[c] * svecs[c];
    ws[OFF_RALL + b * 768 + o] = acc;
  }
}

// ---------------- Wv transpose to f16: WVT[e][d] = qkvw[512+d][e] -----------
__global__ __launch_bounds__(256) void wvt_k(const float* __restrict__ qkvw,
                                             float* __restrict__ ws) {
  int e = blockIdx.x, d = threadIdx.x;
  float v = qkvw[(size_t)(512 + d) * 256 + e];
  ((half_t*)(ws + OFF_WVT))[e * 256 + d] = (half_t)v;
}

// ---------------- Graw = x @ x^T, f16 h-only, symmetric quads ---------------
// grid 768 = (b*8+ks)*3+q ; q0=(0,0) q1=(0,1)+transpose q2=(1,1); K=512/ks
__global__ __launch_bounds__(256) void gram_raw_k(const float* __restrict__ x,
                                                  float* __restrict__ ws) {
  int bid = blockIdx.x;
  int q = bid % 3, bks = bid / 3, ks = bks & 7, b = bks >> 3;
  int qA = (q == 2) ? 1 : 0, qB = (q == 0) ? 0 : 1;
  bool offd = (q == 1);
  __shared__ __align__(16) char Abuf[16384], Bbuf[16384];
  const float* xb = x + (size_t)b * (C_ * (size_t)N_) + ks * 512;
  const float* xA = xb + (size_t)(qA * 128) * N_;
  const float* xB = xb + (size_t)(qB * 128) * N_;
  int t = threadIdx.x, lane = t & 63, w = t >> 6;
  int wm = w >> 1, wn = w & 1, r31 = lane & 31, hi = lane >> 5;
  f32x16 acc[2][2] = {};
  for (int c = 0; c < 8; ++c) {  // 64-k chunks
    {
      const float* src = xA + c * 64;
#pragma unroll
      for (int p = 0; p < 8; ++p) {
        int f = t + p * 256;
        int row = f >> 4, c4 = f & 15;
        float4 v = *(const float4*)(src + (size_t)row * N_ + c4 * 4);
        union { half_t h[4]; uint2 u; } H;
        H.h[0] = (half_t)v.x; H.h[1] = (half_t)v.y;
        H.h[2] = (half_t)v.z; H.h[3] = (half_t)v.w;
        int slot = (c4 >> 1) ^ (row & 7);
        *(uint2*)(Abuf + row * 128 + slot * 16 + (c4 & 1) * 8) = H.u;
      }
      if (offd) {
        const float* srcB = xB + c * 64;
#pragma unroll
        for (int p = 0; p < 8; ++p) {
          int f = t + p * 256;
          int row = f >> 4, c4 = f & 15;
          float4 v = *(const float4*)(srcB + (size_t)row * N_ + c4 * 4);
          union { half_t h[4]; uint2 u; } H;
          H.h[0] = (half_t)v.x; H.h[1] = (half_t)v.y;
          H.h[2] = (half_t)v.z; H.h[3] = (half_t)v.w;
          int slot = (c4 >> 1) ^ (row & 7);
          *(uint2*)(Bbuf + row * 128 + slot * 16 + (c4 & 1) * 8) = H.u;
        }
      }
    }
    __syncthreads();
    const char* Bb = offd ? Bbuf : Abuf;
#pragma unroll
    for (int kk = 0; kk < 4; ++kk) {
      int kb = kk * 32 + hi * 16;
      f16x8 Af[2], Bf[2];
#pragma unroll
      for (int m = 0; m < 2; ++m) {
        int row = wm * 64 + m * 32 + r31;
        Af[m] = *(const f16x8*)(Abuf + row * 128 + (((kb >> 4) ^ (row & 7)) * 16));
      }
#pragma unroll
      for (int n = 0; n < 2; ++n) {
        int row = wn * 64 + n * 32 + r31;
        Bf[n] = *(const f16x8*)(Bb + row * 128 + (((kb >> 4) ^ (row & 7)) * 16));
      }
#pragma unroll
      for (int m = 0; m < 2; ++m)
#pragma unroll
        for (int n = 0; n < 2; ++n)
          acc[m][n] = __builtin_amdgcn_mfma_f32_32x32x16_f16(Af[m], Bf[n], acc[m][n], 0, 0, 0);
    }
    __syncthreads();
  }
  float* G = ws + OFF_GM + (size_t)b * 65536;
#pragma unroll
  for (int m = 0; m < 2; ++m)
#pragma unroll
    for (int n = 0; n < 2; ++n)
#pragma unroll
      for (int r = 0; r < 16; ++r) {
        int gr = qA * 128 + wm * 64 + m * 32 + (r & 3) + 8 * (r >> 2) + 4 * hi;
        int gc = qB * 128 + wn * 64 + n * 32 + r31;
        float v = acc[m][n][r];
        atomicAdd(G + gr * 256 + gc, v);
        if (offd) atomicAdd(G + gc * 256 + gr, v);
      }
}

// ---------------- fused logits: T1=Wq@G, L=T1@Wk^T, softmax, A^T, cv --------
// grid (8 rowblocks, 32 b), 256 thr / 4 waves; wave owns cols w*64..+63
__global__ __launch_bounds__(256) void fused_logits_k(
    const float* __restrict__ qkvw, const float* __restrict__ qkvb,
    float* __restrict__ ws) {
  int b = blockIdx.y, r0 = blockIdx.x * 32;
  int t = threadIdx.x, lane = t & 63, w = t >> 6, r31 = lane & 31, hi = lane >> 5;
  __shared__ __align__(16) char GHL[32768];  // [256][128B]
  __shared__ __align__(16) char AHL[8192];   // A-operand staging
  __shared__ float T1s[32][257];
  __shared__ float scs[256], shs[256], rss[256];
  __shared__ float bk_s[256], rk_s[256], bq_s[32], rq_s[32];
  scs[t] = ws[OFF_SC + b * 256 + t];
  shs[t] = ws[OFF_SH + b * 256 + t];
  rss[t] = ws[OFF_RS + b * 256 + t];
  bk_s[t] = qkvb[256 + t];
  rk_s[t] = ws[OFF_RALL + b * 768 + 256 + t];
  if (t < 32) {
    bq_s[t] = qkvb[r0 + t];
    rq_s[t] = ws[OFF_RALL + b * 768 + r0 + t];
  }
  __syncthreads();
  const float* Graw = ws + OFF_GM + (size_t)b * 65536;
  f32x16 acc[2] = {};
  // ---- step A: T1 = Wq @ G(affine), K=256, 32-k chunks ----
  for (int k0 = 0; k0 < 256; k0 += 32) {
    {  // Wq rows r0..r0+31, h|l in [32][128B]
      int row = t >> 3, c4 = t & 7;
      float4 v = *(const float4*)(qkvw + (size_t)(r0 + row) * 256 + k0 + c4 * 4);
      union { half_t h[4]; uint2 u; } H, L;
      float vv[4] = {v.x, v.y, v.z, v.w};
#pragma unroll
      for (int j = 0; j < 4; ++j) {
        half_t h = (half_t)vv[j];
        H.h[j] = h; L.h[j] = (half_t)(vv[j] - (float)h);
      }
      int s8 = row & 7;
      *(uint2*)(AHL + row * 128 + (((c4 >> 1) ^ s8) * 16) + (c4 & 1) * 8) = H.u;
      *(uint2*)(AHL + row * 128 + ((((c4 >> 1) + 4) ^ s8) * 16) + (c4 & 1) * 8) = L.u;
    }
    {  // G rows (d) 0..255 x 32k, affine applied, h|l in [256][128B]
#pragma unroll
      for (int p = 0; p < 8; ++p) {
        int f = t + p * 256;
        int row = f >> 3, c4 = f & 7;
        float4 gv = *(const float4*)(Graw + (size_t)row * 256 + k0 + c4 * 4);
        float scd = scs[row], shd = shs[row], rsd = rss[row];
        union { half_t h[4]; uint2 u; } H, L;
        float gvv[4] = {gv.x, gv.y, gv.z, gv.w};
#pragma unroll
        for (int j = 0; j < 4; ++j) {
          int cc = k0 + c4 * 4 + j;
          float scc = scs[cc], shc = shs[cc];
          float val = scc * scd * gvv[j] + scc * shd * rss[cc] +
                      shc * scd * rsd + 4096.f * shc * shd;
          half_t h = (half_t)val;
          H.h[j] = h; L.h[j] = (half_t)(val - (float)h);
        }
        int s8 = row & 7;
        *(uint2*)(GHL + row * 128 + (((c4 >> 1) ^ s8) * 16) + (c4 & 1) * 8) = H.u;
        *(uint2*)(GHL + row * 128 + ((((c4 >> 1) + 4) ^ s8) * 16) + (c4 & 1) * 8) = L.u;
      }
    }
    __syncthreads();
#pragma unroll
    for (int kk = 0; kk < 2; ++kk) {
      int kb = kk * 32 + hi * 16;  // byte in 64B h-space
      int arow = r31;
      f16x8 Aq = *(const f16x8*)(AHL + arow * 128 + (((kb >> 4) ^ (arow & 7)) * 16));
#pragma unroll
      for (int n = 0; n < 2; ++n) {
        int row = w * 64 + n * 32 + r31;
        int s8 = row & 7;
        f16x8 Bh = *(const f16x8*)(GHL + row * 128 + (((kb >> 4) ^ s8) * 16));
        f16x8 Bl = *(const f16x8*)(GHL + row * 128 + ((((kb >> 4) + 4) ^ s8) * 16));
        acc[n] = __builtin_amdgcn_mfma_f32_32x32x16_f16(Aq, Bh, acc[n], 0, 0, 0);
        acc[n] = __builtin_amdgcn_mfma_f32_32x32x16_f16(Aq, Bl, acc[n], 0, 0, 0);
      }
    }
    __syncthreads();
  }
#pragma unroll
  for (int n = 0; n < 2; ++n)
#pragma unroll
    for (int r = 0; r < 16; ++r)
      T1s[(r & 3) + 8 * (r >> 2) + 4 * hi][w * 64 + n * 32 + r31] = acc[n][r];
  __syncthreads();
  // ---- step B: L = T1 @ Wk^T, K=256, 64-k chunks ----
  f32x16 acc2[2] = {};
  for (int k0 = 0; k0 < 256; k0 += 64) {
    {  // T1 rows 0..31 x 64k -> h|l in [32][256B], 16-slot swizzle
      int row = t >> 3;
#pragma unroll
      for (int u = 0; u < 2; ++u) {
        int c4 = (t & 7) + u * 8;
        float vv[4];
#pragma unroll
        for (int j = 0; j < 4; ++j) vv[j] = T1s[row][k0 + c4 * 4 + j];
        union { half_t h[4]; uint2 u2; } H, L;
#pragma unroll
        for (int j = 0; j < 4; ++j) {
          half_t h = (half_t)vv[j];
          H.h[j] = h; L.h[j] = (half_t)(vv[j] - (float)h);
        }
        int s16 = row & 15;
        *(uint2*)(AHL + row * 256 + (((c4 >> 1) ^ s16) * 16) + (c4 & 1) * 8) = H.u2;
        *(uint2*)(AHL + row * 256 + ((((c4 >> 1) + 8) ^ s16) * 16) + (c4 & 1) * 8) = L.u2;
      }
    }
    {  // Wk rows j 0..255 x 64k h-only -> [256][128B]
#pragma unroll
      for (int p = 0; p < 16; ++p) {
        int f = t + p * 256;
        int row = f >> 4, c4 = f & 15;
        float4 v = *(const float4*)(qkvw + (size_t)(256 + row) * 256 + k0 + c4 * 4);
        union { half_t h[4]; uint2 u; } H;
        H.h[0] = (half_t)v.x; H.h[1] = (half_t)v.y;
        H.h[2] = (half_t)v.z; H.h[3] = (half_t)v.w;
        int slot = (c4 >> 1) ^ (row & 7);
        *(uint2*)(GHL + row * 128 + slot * 16 + (c4 & 1) * 8) = H.u;
      }
    }
    __syncthreads();
#pragma unroll
    for (int kk = 0; kk < 4; ++kk) {
      int kb = kk * 32 + hi * 16;  // byte in 128B h-space
      int arow = r31;
      int s16 = arow & 15;
      f16x8 Ah = *(const f16x8*)(AHL + arow * 256 + (((kb >> 4) ^ s16) * 16));
      f16x8 Al = *(const f16x8*)(AHL + arow * 256 + ((((kb >> 4) + 8) ^ s16) * 16));
#pragma unroll
      for (int n = 0; n < 2; ++n) {
        int row = w * 64 + n * 32 + r31;
        f16x8 Bf = *(const f16x8*)(GHL + row * 128 + (((kb >> 4) ^ (row & 7)) * 16));
        acc2[n] = __builtin_amdgcn_mfma_f32_32x32x16_f16(Ah, Bf, acc2[n], 0, 0, 0);
        acc2[n] = __builtin_amdgcn_mfma_f32_32x32x16_f16(Al, Bf, acc2[n], 0, 0, 0);
      }
    }
    __syncthreads();
  }
  // corrections + store logits to T1s
#pragma unroll
  for (int n = 0; n < 2; ++n)
#pragma unroll
    for (int r = 0; r < 16; ++r) {
      int rr = (r & 3) + 8 * (r >> 2) + 4 * hi;
      int cc = w * 64 + n * 32 + r31;
      float v = acc2[n][r];
      v = (v + bq_s[rr] * rk_s[cc] + bk_s[cc] * rq_s[rr] +
           4096.f * bq_s[rr] * bk_s[cc]) * SCALE;
      T1s[rr][cc] = v;
    }
  // reload v-bias for cv while waiting
  __syncthreads();
  bk_s[t] = qkvb[512 + t];
  __syncthreads();
  {  // softmax: 8 threads per row
    int row = t >> 3, ls = t & 7;
    float m = -1e30f;
#pragma unroll
    for (int i = 0; i < 32; ++i) m = fmaxf(m, T1s[row][ls + i * 8]);
    m = fmaxf(m, __shfl_xor(m, 1));
    m = fmaxf(m, __shfl_xor(m, 2));
    m = fmaxf(m, __shfl_xor(m, 4));
    float s = 0.f, cvp = 0.f;
#pragma unroll
    for (int i = 0; i < 32; ++i) {
      int col = ls + i * 8;
      float e = __expf(T1s[row][col] - m);
      T1s[row][col] = e;
      s += e;
      cvp += e * bk_s[col];
    }
    s += __shfl_xor(s, 1); s += __shfl_xor(s, 2); s += __shfl_xor(s, 4);
    cvp += __shfl_xor(cvp, 1); cvp += __shfl_xor(cvp, 2); cvp += __shfl_xor(cvp, 4);
    float inv = 1.f / s;
#pragma unroll
    for (int i = 0; i < 32; ++i) T1s[row][ls + i * 8] *= inv;
    if (ls == 0) ws[OFF_CV + b * 256 + r0 + row] = cvp * inv;
  }
  __syncthreads();
  {  // transposed write: AT[b][j][r0..r0+31]
    float* ATb = ws + OFF_AT + (size_t)b * 65536;
#pragma unroll
    for (int u = 0; u < 8; ++u) {
      float4 v = {T1s[u * 4 + 0][t], T1s[u * 4 + 1][t], T1s[u * 4 + 2][t],
                  T1s[u * 4 + 3][t]};
      *(float4*)(ATb + (size_t)t * 256 + r0 + u * 4) = v;
    }
  }
}

// ---------------- fused S: T2=Pw@A, S=T2@Wv (f16 out), const ----------------
__global__ __launch_bounds__(256) void fused_s_k(const float* __restrict__ pw,
                                                 const float* __restrict__ pb,
                                                 float* __restrict__ ws) {
  int b = blockIdx.y, r0 = blockIdx.x * 32;
  int t = threadIdx.x, lane = t & 63, w = t >> 6, r31 = lane & 31, hi = lane >> 5;
  __shared__ __align__(16) char GHL[32768];
  __shared__ __align__(16) char AHL[8192];
  __shared__ float T1s[32][257];
  __shared__ float cvs[256];
  cvs[t] = ws[OFF_CV + b * 256 + t];
  __syncthreads();
  const float* ATb = ws + OFF_AT + (size_t)b * 65536;
  f32x16 acc[2] = {};
  // ---- step A: T2 = Pw @ A, K=256, 64-k chunks, all h-only ----
  for (int k0 = 0; k0 < 256; k0 += 64) {
    {  // Pw rows r0..+31 x 64k -> [32][128B]
#pragma unroll
      for (int p = 0; p < 2; ++p) {
        int f = t + p * 256;
        int row = f >> 4, c4 = f & 15;
        float4 v = *(const float4*)(pw + (size_t)(r0 + row) * 256 + k0 + c4 * 4);
        union { half_t h[4]; uint2 u; } H;
        H.h[0] = (half_t)v.x; H.h[1] = (half_t)v.y;
        H.h[2] = (half_t)v.z; H.h[3] = (half_t)v.w;
        int slot = (c4 >> 1) ^ (row & 7);
        *(uint2*)(AHL + row * 128 + slot * 16 + (c4 & 1) * 8) = H.u;
      }
    }
    {  // A^T rows j 0..255 x 64c -> [256][128B]
#pragma unroll
      for (int p = 0; p < 16; ++p) {
        int f = t + p * 256;
        int row = f >> 4, c4 = f & 15;
        float4 v = *(const float4*)(ATb + (size_t)row * 256 + k0 + c4 * 4);
        union { half_t h[4]; uint2 u; } H;
        H.h[0] = (half_t)v.x; H.h[1] = (half_t)v.y;
        H.h[2] = (half_t)v.z; H.h[3] = (half_t)v.w;
        int slot = (c4 >> 1) ^ (row & 7);
        *(uint2*)(GHL + row * 128 + slot * 16 + (c4 & 1) * 8) = H.u;
      }
    }
    __syncthreads();
#pragma unroll
    for (int kk = 0; kk < 4; ++kk) {
      int kb = kk * 32 + hi * 16;
      int arow = r31;
      f16x8 Af = *(const f16x8*)(AHL + arow * 128 + (((kb >> 4) ^ (arow & 7)) * 16));
#pragma unroll
      for (int n = 0; n < 2; ++n) {
        int row = w * 64 + n * 32 + r31;
        f16x8 Bf = *(const f16x8*)(GHL + row * 128 + (((kb >> 4) ^ (row & 7)) * 16));
        acc[n] = __builtin_amdgcn_mfma_f32_32x32x16_f16(Af, Bf, acc[n], 0, 0, 0);
      }
    }
    __syncthreads();
  }
#pragma unroll
  for (int n = 0; n < 2; ++n)
#pragma unroll
    for (int r = 0; r < 16; ++r)
      T1s[(r & 3) + 8 * (r >> 2) + 4 * hi][w * 64 + n * 32 + r31] = acc[n][r];
  __syncthreads();
  {  // const[b, r0+row] = pb + Pw[row] @ cv
    int row = t >> 3, ls = t & 7;
    float a = 0.f;
#pragma unroll
    for (int i = 0; i < 32; ++i) {
      int c = ls + i * 8;
      a += pw[(size_t)(r0 + row) * 256 + c] * cvs[c];
    }
    a += __shfl_xor(a, 1); a += __shfl_xor(a, 2); a += __shfl_xor(a, 4);
    if (ls == 0) ws[OFF_CONST + b * 256 + r0 + row] = a + pb[r0 + row];
  }
  // ---- step B: S = T2 @ Wv (WVT staged), K=256, 64-k chunks ----
  const half_t* WVT = (const half_t*)(ws + OFF_WVT);
  f32x16 acc2[2] = {};
  for (int k0 = 0; k0 < 256; k0 += 64) {
    {  // T2 rows 0..31 x 64k -> h|l [32][256B]
      int row = t >> 3;
#pragma unroll
      for (int u = 0; u < 2; ++u) {
        int c4 = (t & 7) + u * 8;
        float vv[4];
#pragma unroll
        for (int j = 0; j < 4; ++j) vv[j] = T1s[row][k0 + c4 * 4 + j];
        union { half_t h[4]; uint2 u2; } H, L;
#pragma unroll
        for (int j = 0; j < 4; ++j) {
          half_t h = (half_t)vv[j];
          H.h[j] = h; L.h[j] = (half_t)(vv[j] - (float)h);
        }
        int s16 = row & 15;
        *(uint2*)(AHL + row * 256 + (((c4 >> 1) ^ s16) * 16) + (c4 & 1) * 8) = H.u2;
        *(uint2*)(AHL + row * 256 + ((((c4 >> 1) + 8) ^ s16) * 16) + (c4 & 1) * 8) = L.u2;
      }
    }
    {  // WVT rows e 0..255 x 64d (f16 already) -> [256][128B]
#pragma unroll
      for (int p = 0; p < 8; ++p) {
        int f = t + p * 256;
        int row = f >> 3, h8 = f & 7;
        uint2 v = *(const uint2*)(WVT + (size_t)row * 256 + k0 + h8 * 8);
        uint2 v2 = *(const uint2*)(WVT + (size_t)row * 256 + k0 + h8 * 8 + 4);
        int slot = h8 ^ (row & 7);
        *(uint2*)(GHL + row * 128 + slot * 16) = v;
        *(uint2*)(GHL + row * 128 + slot * 16 + 8) = v2;
      }
    }
    __syncthreads();
#pragma unroll
    for (int kk = 0; kk < 4; ++kk) {
      int kb = kk * 32 + hi * 16;
      int arow = r31;
      int s16 = arow & 15;
      f16x8 Ah = *(const f16x8*)(AHL + arow * 256 + (((kb >> 4) ^ s16) * 16));
      f16x8 Al = *(const f16x8*)(AHL + arow * 256 + ((((kb >> 4) + 8) ^ s16) * 16));
#pragma unroll
      for (int n = 0; n < 2; ++n) {
        int row = w * 64 + n * 32 + r31;
        f16x8 Bf = *(const f16x8*)(GHL + row * 128 + (((kb >> 4) ^ (row & 7)) * 16));
        acc2[n] = __builtin_amdgcn_mfma_f32_32x32x16_f16(Ah, Bf, acc2[n], 0, 0, 0);
        acc2[n] = __builtin_amdgcn_mfma_f32_32x32x16_f16(Al, Bf, acc2[n], 0, 0, 0);
      }
    }
    __syncthreads();
  }
#pragma unroll
  for (int n = 0; n < 2; ++n)
#pragma unroll
    for (int r = 0; r < 16; ++r)
      T1s[(r & 3) + 8 * (r >> 2) + 4 * hi][w * 64 + n * 32 + r31] = acc2[n][r];
  __syncthreads();
  {  // pack S -> f16 [o][c]
    half_t* Sb = (half_t*)(ws + OFF_S16) + (size_t)b * 65536;
    int row = t >> 3, seg = t & 7;
#pragma unroll
    for (int u = 0; u < 4; ++u) {
      union { half_t h[8]; uint4 v; } P;
#pragma unroll
      for (int j = 0; j < 8; ++j)
        P.h[j] = (half_t)T1s[row][seg * 32 + u * 8 + j];
      *(uint4*)(Sb + (size_t)(r0 + row) * 256 + seg * 32 + u * 8) = P.v;
    }
  }
}

// ---------------- final: out = x + S[b] @ xn + const, f16 MFMA --------------
__global__ __launch_bounds__(256, 3) void final_mfma_k(
    const float* __restrict__ x, float* __restrict__ out,
    const float* __restrict__ ws) {
  __shared__ __align__(16) char Bt[16384];  // [64 n][256B] swizzled
  int b = blockIdx.y, n0 = blockIdx.x * 64;
  int t = threadIdx.x, lane = t & 63, w = t >> 6;
  int r31 = lane & 31, hi = lane >> 5;
  const half_t* Shb = (const half_t*)(ws + OFF_S16) + (size_t)b * 65536;
  const float* xb = x + (size_t)b * (C_ * (size_t)N_);
  const float* scb = ws + OFF_SC + b * 256;
  const float* shb = ws + OFF_SH + b * 256;
  f32x16 acc[2][2] = {};
  for (int c0 = 0; c0 < 256; c0 += 128) {
#pragma unroll
    for (int p = 0; p < 8; ++p) {
      int f = t + p * 256;
      int cl = f >> 4, j4 = f & 15;
      int c = c0 + cl;
      float4 v = *(const float4*)(xb + (size_t)c * N_ + n0 + j4 * 4);
      float sc = scb[c], sh = shb[c];
      float vv[4] = {v.x * sc + sh, v.y * sc + sh, v.z * sc + sh, v.w * sc + sh};
      int cb = cl * 2, b16 = cb & ~15, off = cb & 15;
#pragma unroll
      for (int e = 0; e < 4; ++e) {
        int nn = j4 * 4 + e;
        *(half_t*)(Bt + nn * 256 + (b16 ^ ((nn & 15) << 4)) + off) = (half_t)vv[e];
      }
    }
    __syncthreads();
#pragma unroll
    for (int kk = 0; kk < 8; ++kk) {
      int byte = kk * 32 + hi * 16;
      int cA = c0 + kk * 16 + hi * 8;
      f16x8 Af[2], Bf[2];
#pragma unroll
      for (int m = 0; m < 2; ++m) {
        int o = w * 64 + m * 32 + r31;
        Af[m] = *(const f16x8*)(Shb + (size_t)o * 256 + cA);
      }
#pragma unroll
      for (int n = 0; n < 2; ++n) {
        int nn = n * 32 + r31;
        Bf[n] = *(const f16x8*)(Bt + nn * 256 + (byte ^ ((nn & 15) << 4)));
      }
#pragma unroll
      for (int m = 0; m < 2; ++m)
#pragma unroll
        for (int n = 0; n < 2; ++n)
          acc[m][n] = __builtin_amdgcn_mfma_f32_32x32x16_f16(Af[m], Bf[n], acc[m][n], 0, 0, 0);
    }
    __syncthreads();
  }
  float* ob = out + (size_t)b * (C_ * (size_t)N_);
  const float* cstb = ws + OFF_CONST + b * 256;
#pragma unroll
  for (int m = 0; m < 2; ++m)
#pragma unroll
    for (int r = 0; r < 16; ++r) {
      int o = w * 64 + m * 32 + (r & 3) + 8 * (r >> 2) + 4 * hi;
      float cv = cstb[o];
      size_t base = (size_t)o * N_ + n0;
#pragma unroll
      for (int n = 0; n < 2; ++n) {
        int col = n * 32 + r31;
        ob[base + col] = acc[m][n][r] + xb[base + col] + cv;
      }
    }
}

extern "C" void kernel_launch(void* const* d_in, const int* in_sizes, int n_in,
                              void* d_out, int out_size, void* d_ws,
                              size_t ws_size, hipStream_t stream) {
  const float* x = (const float*)d_in[0];
  const float* gw = (const float*)d_in[1];
  const float* gb = (const float*)d_in[2];
  const float* qkvw = (const float*)d_in[3];
  const float* qkvb = (const float*)d_in[4];
  const float* pw = (const float*)d_in[5];
  const float* pb = (const float*)d_in[6];
  float* out = (float*)d_out;
  float* ws = (float*)d_ws;

  hipMemsetAsync(ws + OFF_GM, 0, (size_t)32 * 65536 * 4, stream);
  hipLaunchKernelGGL(stats_part_k, dim3(1024), dim3(256), 0, stream, x, ws);
  hipLaunchKernelGGL(prep_k, dim3(32), dim3(256), 0, stream, gw, gb, qkvw, ws);
  hipLaunchKernelGGL(wvt_k, dim3(256), dim3(256), 0, stream, qkvw, ws);
  hipLaunchKernelGGL(gram_raw_k, dim3(768), dim3(256), 0, stream, x, ws);
  hipLaunchKernelGGL(fused_logits_k, dim3(8, 32), dim3(256), 0, stream, qkvw, qkvb, ws);
  hipLaunchKernelGGL(fused_s_k, dim3(8, 32), dim3(256), 0, stream, pw, pb, ws);
  hipLaunchKernelGGL(final_mfma_k, dim3(64, 32), dim3(256), 0, stream, x, out, ws);
}

// Round 5
// 251.953 us; speedup vs baseline: 1.4301x; 1.4301x over previous
//
#include <hip/hip_runtime.h>

// SelfAttention block, fully restructured:
//   gram_v4 : Graw slabs = x @ x^T per (b,K-slice), f16 MFMA, prefetch-pipelined,
//             also emits per-channel sum/sumsq partials (no separate stats pass)
//   prep    : group stats -> sc/sh, svec, rall (sums slice partials)
//   gsum    : G[b] = sum of 8 f16 slabs (fp32 out)
//   fused_logits: T1=Wq@G(affine on the fly), L=T1@Wk^T +corr, softmax, A^T, cv
//   fused_s : T2=Pw@A, S=T2@Wv -> f16, const[b,o]
//   final   : out = x + S@xn + const  (f16 MFMA)

#define B_ 32
#define C_ 256
#define N_ 4096
#define GSIZE (32 * N_)
#define EPSV 1e-5f
#define SCALE 0.0625f

// workspace layout (float units)
#define OFF_SC    0
#define OFF_SH    8192
#define OFF_RS    16384
#define OFF_RSP   24576                 // [b*8+ks][256]
#define OFF_SQP   90112                 // [b*8+ks][256]
#define OFF_RALL  155648
#define OFF_CV    180224
#define OFF_CONST 188416
#define OFF_WVT   196608                // f16 [256][256]
#define OFF_GM    229376                // fp32 [b][256][256]
#define OFF_AT    2326528               // fp32 [b][j][r]
#define OFF_S16   4423680               // f16 [b][o][c]
#define OFF_GP    5472256               // f16 slabs [b*8+ks][65536]

typedef _Float16 half_t;
typedef half_t f16x8 __attribute__((ext_vector_type(8)));
typedef float f32x16 __attribute__((ext_vector_type(16)));

// ---------------- Gram partials, pipelined --------------------------------
// grid 256 = b*8+ks (K=512 each); 512 thr / 8 waves (2x4 of 128x64 tiles).
// Chunk c (64 k) lives in stg[c&1] and hb[c&1]:
//   prologue: load c0->stg0, c1->stg1, write c0->hb0
//   step c:   MFMA hb[c&1]; write stg[(c+1)&1]->hb[(c+1)&1]; load c+2->stg[c&1]
__global__ __launch_bounds__(512, 1) void gram_v4_k(const float* __restrict__ x,
                                                    float* __restrict__ ws) {
  __shared__ __align__(16) char hb[2][32768];  // [buf][256 rows][128B] swizzled
  int b = blockIdx.x >> 3, ks = blockIdx.x & 7;
  int t = threadIdx.x;
  const float* xb = x + (size_t)b * (C_ * (size_t)N_) + ks * 512;
  int lane = t & 63, w = t >> 6;
  int wm = w >> 2, wn = w & 3, r31 = lane & 31, hi = lane >> 5;
  int lrow = t >> 4, lc4 = t & 15;
  const float* lbase = xb + (size_t)lrow * N_ + lc4 * 4;
  f32x16 acc[4][2] = {};
  float4 stg[2][8];
  float rs[8] = {0.f, 0.f, 0.f, 0.f, 0.f, 0.f, 0.f, 0.f};
  float rq[8] = {0.f, 0.f, 0.f, 0.f, 0.f, 0.f, 0.f, 0.f};

#define LOADV(sb, c)                                                      \
  _Pragma("unroll") for (int p = 0; p < 8; ++p)                           \
      stg[sb][p] = *(const float4*)(lbase + (size_t)p * 32 * N_ + (c) * 64);

#define WRITEV(sb, buf)                                                   \
  {                                                                       \
    char* bp = hb[buf];                                                   \
    _Pragma("unroll") for (int p = 0; p < 8; ++p) {                       \
      float4 v = stg[sb][p];                                              \
      rs[p] += v.x + v.y + v.z + v.w;                                     \
      rq[p] += v.x * v.x + v.y * v.y + v.z * v.z + v.w * v.w;             \
      union { half_t h[4]; uint2 u; } H;                                  \
      H.h[0] = (half_t)v.x; H.h[1] = (half_t)v.y;                         \
      H.h[2] = (half_t)v.z; H.h[3] = (half_t)v.w;                         \
      int row = lrow + p * 32;                                            \
      int slot = (lc4 >> 1) ^ (row & 7);                                  \
      *(uint2*)(bp + row * 128 + slot * 16 + (lc4 & 1) * 8) = H.u;        \
    }                                                                     \
  }

  LOADV(0, 0);
  LOADV(1, 1);
  WRITEV(0, 0);
  __syncthreads();
  for (int c = 0; c < 8; ++c) {
    int buf = c & 1;
#pragma unroll
    for (int kk = 0; kk < 4; ++kk) {
      int kb = kk * 32 + hi * 16;
      f16x8 Af[4], Bf[2];
#pragma unroll
      for (int m = 0; m < 4; ++m) {
        int row = wm * 128 + m * 32 + r31;
        Af[m] = *(const f16x8*)(hb[buf] + row * 128 + (((kb >> 4) ^ (row & 7)) * 16));
      }
#pragma unroll
      for (int n = 0; n < 2; ++n) {
        int row = wn * 64 + n * 32 + r31;
        Bf[n] = *(const f16x8*)(hb[buf] + row * 128 + (((kb >> 4) ^ (row & 7)) * 16));
      }
#pragma unroll
      for (int m = 0; m < 4; ++m)
#pragma unroll
        for (int n = 0; n < 2; ++n)
          acc[m][n] = __builtin_amdgcn_mfma_f32_32x32x16_f16(Af[m], Bf[n], acc[m][n], 0, 0, 0);
    }
    if (c < 7) {
      int nb = (c + 1) & 1;          // buffer/staging holding chunk c+1
      WRITEV(nb, nb);
      if (c < 6) LOADV(buf, c + 2);  // chunk c+2 has parity c&1 -> stg[buf]
      __syncthreads();
    }
  }
  // per-channel sum/sumsq partials for this K-slice
#pragma unroll
  for (int p = 0; p < 8; ++p) {
    float s = rs[p], q = rq[p];
    s += __shfl_xor(s, 1); s += __shfl_xor(s, 2);
    s += __shfl_xor(s, 4); s += __shfl_xor(s, 8);
    q += __shfl_xor(q, 1); q += __shfl_xor(q, 2);
    q += __shfl_xor(q, 4); q += __shfl_xor(q, 8);
    if ((t & 15) == 0) {
      int row = lrow + p * 32;
      ws[OFF_RSP + (size_t)blockIdx.x * 256 + row] = s;
      ws[OFF_SQP + (size_t)blockIdx.x * 256 + row] = q;
    }
  }
  // partial G -> f16 slab (coalesced 32-lane rows, no atomics)
  half_t* Gp = (half_t*)(ws + OFF_GP) + (size_t)blockIdx.x * 65536;
#pragma unroll
  for (int m = 0; m < 4; ++m)
#pragma unroll
    for (int n = 0; n < 2; ++n)
#pragma unroll
      for (int r = 0; r < 16; ++r) {
        int gr = wm * 128 + m * 32 + (r & 3) + 8 * (r >> 2) + 4 * hi;
        int gc = wn * 64 + n * 32 + r31;
        Gp[gr * 256 + gc] = (half_t)acc[m][n][r];
      }
#undef LOADV
#undef WRITEV
}

// ---------------- G[b] = sum of 8 slabs -------------------------------------
__global__ __launch_bounds__(256) void gsum_k(float* __restrict__ ws) {
  int bx = blockIdx.x;  // 2048 = 32 b x 64 seg
  int b = bx >> 6, seg = bx & 63;
  int e0 = seg * 1024 + threadIdx.x * 4;
  const half_t* Gp = (const half_t*)(ws + OFF_GP) + (size_t)b * 8 * 65536 + e0;
  float4 s = {0.f, 0.f, 0.f, 0.f};
#pragma unroll
  for (int ks = 0; ks < 8; ++ks) {
    union { uint2 u; half_t h[4]; } P;
    P.u = *(const uint2*)(Gp + (size_t)ks * 65536);
    s.x += (float)P.h[0]; s.y += (float)P.h[1];
    s.z += (float)P.h[2]; s.w += (float)P.h[3];
  }
  *(float4*)(ws + OFF_GM + (size_t)b * 65536 + e0) = s;
}

// ---------------- prep: stats -> sc/sh, svec, rall --------------------------
__global__ __launch_bounds__(256) void prep_k(const float* __restrict__ gw,
                                              const float* __restrict__ gb,
                                              const float* __restrict__ qkvw,
                                              float* __restrict__ ws) {
  int b = blockIdx.x, t = threadIdx.x;
  __shared__ float sL[256], qL[256], svecs[256], gmean[8], grstd[8];
  float s = 0.f, q = 0.f;
#pragma unroll
  for (int ks = 0; ks < 8; ++ks) {
    s += ws[OFF_RSP + (b * 8 + ks) * 256 + t];
    q += ws[OFF_SQP + (b * 8 + ks) * 256 + t];
  }
  ws[OFF_RS + b * 256 + t] = s;
  sL[t] = s; qL[t] = q;
  __syncthreads();
  if (t < 8) {
    float gs = 0.f, gq = 0.f;
    for (int i = 0; i < 32; ++i) { gs += sL[t * 32 + i]; gq += qL[t * 32 + i]; }
    float mean = gs * (1.f / GSIZE);
    float var = gq * (1.f / GSIZE) - mean * mean;
    gmean[t] = mean;
    grstd[t] = rsqrtf(var + EPSV);
  }
  __syncthreads();
  int g = t >> 5;
  float sc = grstd[g] * gw[t];
  float sh = gb[t] - gmean[g] * sc;
  ws[OFF_SC + b * 256 + t] = sc;
  ws[OFF_SH + b * 256 + t] = sh;
  float sv = s * sc + 4096.f * sh;
  svecs[t] = sv;
  __syncthreads();
  for (int oo = 0; oo < 3; ++oo) {
    int o = t + oo * 256;
    const float* wr = qkvw + (size_t)o * 256;
    float acc = 0.f;
#pragma unroll 8
    for (int c = 0; c < 256; ++c) acc += wr[c] * svecs[c];
    ws[OFF_RALL + b * 768 + o] = acc;
  }
}

// ---------------- Wv transpose to f16: WVT[e][d] = qkvw[512+d][e] -----------
__global__ __launch_bounds__(256) void wvt_k(const float* __restrict__ qkvw,
                                             float* __restrict__ ws) {
  int e = blockIdx.x, d = threadIdx.x;
  float v = qkvw[(size_t)(512 + d) * 256 + e];
  ((half_t*)(ws + OFF_WVT))[e * 256 + d] = (half_t)v;
}

// ---------------- fused logits: T1=Wq@G, L=T1@Wk^T, softmax, A^T, cv --------
__global__ __launch_bounds__(256) void fused_logits_k(
    const float* __restrict__ qkvw, const float* __restrict__ qkvb,
    float* __restrict__ ws) {
  int b = blockIdx.y, r0 = blockIdx.x * 32;
  int t = threadIdx.x, lane = t & 63, w = t >> 6, r31 = lane & 31, hi = lane >> 5;
  __shared__ __align__(16) char GHL[32768];  // [256][128B]
  __shared__ __align__(16) char AHL[8192];   // A-operand staging
  __shared__ float T1s[32][257];
  __shared__ float scs[256], shs[256], rss[256];
  __shared__ float bk_s[256], rk_s[256], bq_s[32], rq_s[32];
  scs[t] = ws[OFF_SC + b * 256 + t];
  shs[t] = ws[OFF_SH + b * 256 + t];
  rss[t] = ws[OFF_RS + b * 256 + t];
  bk_s[t] = qkvb[256 + t];
  rk_s[t] = ws[OFF_RALL + b * 768 + 256 + t];
  if (t < 32) {
    bq_s[t] = qkvb[r0 + t];
    rq_s[t] = ws[OFF_RALL + b * 768 + r0 + t];
  }
  __syncthreads();
  const float* Graw = ws + OFF_GM + (size_t)b * 65536;
  f32x16 acc[2] = {};
  // ---- step A: T1 = Wq @ G(affine), K=256, 32-k chunks ----
  for (int k0 = 0; k0 < 256; k0 += 32) {
    {  // Wq rows r0..r0+31, h|l in [32][128B]
      int row = t >> 3, c4 = t & 7;
      float4 v = *(const float4*)(qkvw + (size_t)(r0 + row) * 256 + k0 + c4 * 4);
      union { half_t h[4]; uint2 u; } H, L;
      float vv[4] = {v.x, v.y, v.z, v.w};
#pragma unroll
      for (int j = 0; j < 4; ++j) {
        half_t h = (half_t)vv[j];
        H.h[j] = h; L.h[j] = (half_t)(vv[j] - (float)h);
      }
      int s8 = row & 7;
      *(uint2*)(AHL + row * 128 + (((c4 >> 1) ^ s8) * 16) + (c4 & 1) * 8) = H.u;
      *(uint2*)(AHL + row * 128 + ((((c4 >> 1) + 4) ^ s8) * 16) + (c4 & 1) * 8) = L.u;
    }
    {  // G rows (d) 0..255 x 32k, affine applied, h|l in [256][128B]
#pragma unroll
      for (int p = 0; p < 8; ++p) {
        int f = t + p * 256;
        int row = f >> 3, c4 = f & 7;
        float4 gv = *(const float4*)(Graw + (size_t)row * 256 + k0 + c4 * 4);
        float scd = scs[row], shd = shs[row], rsd = rss[row];
        union { half_t h[4]; uint2 u; } H, L;
        float gvv[4] = {gv.x, gv.y, gv.z, gv.w};
#pragma unroll
        for (int j = 0; j < 4; ++j) {
          int cc = k0 + c4 * 4 + j;
          float scc = scs[cc], shc = shs[cc];
          float val = scc * scd * gvv[j] + scc * shd * rss[cc] +
                      shc * scd * rsd + 4096.f * shc * shd;
          half_t h = (half_t)val;
          H.h[j] = h; L.h[j] = (half_t)(val - (float)h);
        }
        int s8 = row & 7;
        *(uint2*)(GHL + row * 128 + (((c4 >> 1) ^ s8) * 16) + (c4 & 1) * 8) = H.u;
        *(uint2*)(GHL + row * 128 + ((((c4 >> 1) + 4) ^ s8) * 16) + (c4 & 1) * 8) = L.u;
      }
    }
    __syncthreads();
#pragma unroll
    for (int kk = 0; kk < 2; ++kk) {
      int kb = kk * 32 + hi * 16;
      int arow = r31;
      f16x8 Aq = *(const f16x8*)(AHL + arow * 128 + (((kb >> 4) ^ (arow & 7)) * 16));
#pragma unroll
      for (int n = 0; n < 2; ++n) {
        int row = w * 64 + n * 32 + r31;
        int s8 = row & 7;
        f16x8 Bh = *(const f16x8*)(GHL + row * 128 + (((kb >> 4) ^ s8) * 16));
        f16x8 Bl = *(const f16x8*)(GHL + row * 128 + ((((kb >> 4) + 4) ^ s8) * 16));
        acc[n] = __builtin_amdgcn_mfma_f32_32x32x16_f16(Aq, Bh, acc[n], 0, 0, 0);
        acc[n] = __builtin_amdgcn_mfma_f32_32x32x16_f16(Aq, Bl, acc[n], 0, 0, 0);
      }
    }
    __syncthreads();
  }
#pragma unroll
  for (int n = 0; n < 2; ++n)
#pragma unroll
    for (int r = 0; r < 16; ++r)
      T1s[(r & 3) + 8 * (r >> 2) + 4 * hi][w * 64 + n * 32 + r31] = acc[n][r];
  __syncthreads();
  // ---- step B: L = T1 @ Wk^T, K=256, 64-k chunks ----
  f32x16 acc2[2] = {};
  for (int k0 = 0; k0 < 256; k0 += 64) {
    {  // T1 rows 0..31 x 64k -> h|l in [32][256B], 16-slot swizzle
      int row = t >> 3;
#pragma unroll
      for (int u = 0; u < 2; ++u) {
        int c4 = (t & 7) + u * 8;
        float vv[4];
#pragma unroll
        for (int j = 0; j < 4; ++j) vv[j] = T1s[row][k0 + c4 * 4 + j];
        union { half_t h[4]; uint2 u2; } H, L;
#pragma unroll
        for (int j = 0; j < 4; ++j) {
          half_t h = (half_t)vv[j];
          H.h[j] = h; L.h[j] = (half_t)(vv[j] - (float)h);
        }
        int s16 = row & 15;
        *(uint2*)(AHL + row * 256 + (((c4 >> 1) ^ s16) * 16) + (c4 & 1) * 8) = H.u2;
        *(uint2*)(AHL + row * 256 + ((((c4 >> 1) + 8) ^ s16) * 16) + (c4 & 1) * 8) = L.u2;
      }
    }
    {  // Wk rows j 0..255 x 64k h-only -> [256][128B]
#pragma unroll
      for (int p = 0; p < 16; ++p) {
        int f = t + p * 256;
        int row = f >> 4, c4 = f & 15;
        float4 v = *(const float4*)(qkvw + (size_t)(256 + row) * 256 + k0 + c4 * 4);
        union { half_t h[4]; uint2 u; } H;
        H.h[0] = (half_t)v.x; H.h[1] = (half_t)v.y;
        H.h[2] = (half_t)v.z; H.h[3] = (half_t)v.w;
        int slot = (c4 >> 1) ^ (row & 7);
        *(uint2*)(GHL + row * 128 + slot * 16 + (c4 & 1) * 8) = H.u;
      }
    }
    __syncthreads();
#pragma unroll
    for (int kk = 0; kk < 4; ++kk) {
      int kb = kk * 32 + hi * 16;
      int arow = r31;
      int s16 = arow & 15;
      f16x8 Ah = *(const f16x8*)(AHL + arow * 256 + (((kb >> 4) ^ s16) * 16));
      f16x8 Al = *(const f16x8*)(AHL + arow * 256 + ((((kb >> 4) + 8) ^ s16) * 16));
#pragma unroll
      for (int n = 0; n < 2; ++n) {
        int row = w * 64 + n * 32 + r31;
        f16x8 Bf = *(const f16x8*)(GHL + row * 128 + (((kb >> 4) ^ (row & 7)) * 16));
        acc2[n] = __builtin_amdgcn_mfma_f32_32x32x16_f16(Ah, Bf, acc2[n], 0, 0, 0);
        acc2[n] = __builtin_amdgcn_mfma_f32_32x32x16_f16(Al, Bf, acc2[n], 0, 0, 0);
      }
    }
    __syncthreads();
  }
#pragma unroll
  for (int n = 0; n < 2; ++n)
#pragma unroll
    for (int r = 0; r < 16; ++r) {
      int rr = (r & 3) + 8 * (r >> 2) + 4 * hi;
      int cc = w * 64 + n * 32 + r31;
      float v = acc2[n][r];
      v = (v + bq_s[rr] * rk_s[cc] + bk_s[cc] * rq_s[rr] +
           4096.f * bq_s[rr] * bk_s[cc]) * SCALE;
      T1s[rr][cc] = v;
    }
  __syncthreads();
  bk_s[t] = qkvb[512 + t];
  __syncthreads();
  {  // softmax: 8 threads per row
    int row = t >> 3, ls = t & 7;
    float m = -1e30f;
#pragma unroll
    for (int i = 0; i < 32; ++i) m = fmaxf(m, T1s[row][ls + i * 8]);
    m = fmaxf(m, __shfl_xor(m, 1));
    m = fmaxf(m, __shfl_xor(m, 2));
    m = fmaxf(m, __shfl_xor(m, 4));
    float s = 0.f, cvp = 0.f;
#pragma unroll
    for (int i = 0; i < 32; ++i) {
      int col = ls + i * 8;
      float e = __expf(T1s[row][col] - m);
      T1s[row][col] = e;
      s += e;
      cvp += e * bk_s[col];
    }
    s += __shfl_xor(s, 1); s += __shfl_xor(s, 2); s += __shfl_xor(s, 4);
    cvp += __shfl_xor(cvp, 1); cvp += __shfl_xor(cvp, 2); cvp += __shfl_xor(cvp, 4);
    float inv = 1.f / s;
#pragma unroll
    for (int i = 0; i < 32; ++i) T1s[row][ls + i * 8] *= inv;
    if (ls == 0) ws[OFF_CV + b * 256 + r0 + row] = cvp * inv;
  }
  __syncthreads();
  {  // transposed write: AT[b][j][r0..r0+31]
    float* ATb = ws + OFF_AT + (size_t)b * 65536;
#pragma unroll
    for (int u = 0; u < 8; ++u) {
      float4 v = {T1s[u * 4 + 0][t], T1s[u * 4 + 1][t], T1s[u * 4 + 2][t],
                  T1s[u * 4 + 3][t]};
      *(float4*)(ATb + (size_t)t * 256 + r0 + u * 4) = v;
    }
  }
}

// ---------------- fused S: T2=Pw@A, S=T2@Wv (f16 out), const ----------------
__global__ __launch_bounds__(256) void fused_s_k(const float* __restrict__ pw,
                                                 const float* __restrict__ pb,
                                                 float* __restrict__ ws) {
  int b = blockIdx.y, r0 = blockIdx.x * 32;
  int t = threadIdx.x, lane = t & 63, w = t >> 6, r31 = lane & 31, hi = lane >> 5;
  __shared__ __align__(16) char GHL[32768];
  __shared__ __align__(16) char AHL[8192];
  __shared__ float T1s[32][257];
  __shared__ float cvs[256];
  cvs[t] = ws[OFF_CV + b * 256 + t];
  __syncthreads();
  const float* ATb = ws + OFF_AT + (size_t)b * 65536;
  f32x16 acc[2] = {};
  // ---- step A: T2 = Pw @ A, K=256, 64-k chunks, all h-only ----
  for (int k0 = 0; k0 < 256; k0 += 64) {
    {
#pragma unroll
      for (int p = 0; p < 2; ++p) {
        int f = t + p * 256;
        int row = f >> 4, c4 = f & 15;
        float4 v = *(const float4*)(pw + (size_t)(r0 + row) * 256 + k0 + c4 * 4);
        union { half_t h[4]; uint2 u; } H;
        H.h[0] = (half_t)v.x; H.h[1] = (half_t)v.y;
        H.h[2] = (half_t)v.z; H.h[3] = (half_t)v.w;
        int slot = (c4 >> 1) ^ (row & 7);
        *(uint2*)(AHL + row * 128 + slot * 16 + (c4 & 1) * 8) = H.u;
      }
    }
    {
#pragma unroll
      for (int p = 0; p < 16; ++p) {
        int f = t + p * 256;
        int row = f >> 4, c4 = f & 15;
        float4 v = *(const float4*)(ATb + (size_t)row * 256 + k0 + c4 * 4);
        union { half_t h[4]; uint2 u; } H;
        H.h[0] = (half_t)v.x; H.h[1] = (half_t)v.y;
        H.h[2] = (half_t)v.z; H.h[3] = (half_t)v.w;
        int slot = (c4 >> 1) ^ (row & 7);
        *(uint2*)(GHL + row * 128 + slot * 16 + (c4 & 1) * 8) = H.u;
      }
    }
    __syncthreads();
#pragma unroll
    for (int kk = 0; kk < 4; ++kk) {
      int kb = kk * 32 + hi * 16;
      int arow = r31;
      f16x8 Af = *(const f16x8*)(AHL + arow * 128 + (((kb >> 4) ^ (arow & 7)) * 16));
#pragma unroll
      for (int n = 0; n < 2; ++n) {
        int row = w * 64 + n * 32 + r31;
        f16x8 Bf = *(const f16x8*)(GHL + row * 128 + (((kb >> 4) ^ (row & 7)) * 16));
        acc[n] = __builtin_amdgcn_mfma_f32_32x32x16_f16(Af, Bf, acc[n], 0, 0, 0);
      }
    }
    __syncthreads();
  }
#pragma unroll
  for (int n = 0; n < 2; ++n)
#pragma unroll
    for (int r = 0; r < 16; ++r)
      T1s[(r & 3) + 8 * (r >> 2) + 4 * hi][w * 64 + n * 32 + r31] = acc[n][r];
  __syncthreads();
  {  // const[b, r0+row] = pb + Pw[row] @ cv
    int row = t >> 3, ls = t & 7;
    float a = 0.f;
#pragma unroll
    for (int i = 0; i < 32; ++i) {
      int c = ls + i * 8;
      a += pw[(size_t)(r0 + row) * 256 + c] * cvs[c];
    }
    a += __shfl_xor(a, 1); a += __shfl_xor(a, 2); a += __shfl_xor(a, 4);
    if (ls == 0) ws[OFF_CONST + b * 256 + r0 + row] = a + pb[r0 + row];
  }
  // ---- step B: S = T2 @ Wv (WVT staged), K=256, 64-k chunks ----
  const half_t* WVT = (const half_t*)(ws + OFF_WVT);
  f32x16 acc2[2] = {};
  for (int k0 = 0; k0 < 256; k0 += 64) {
    {
      int row = t >> 3;
#pragma unroll
      for (int u = 0; u < 2; ++u) {
        int c4 = (t & 7) + u * 8;
        float vv[4];
#pragma unroll
        for (int j = 0; j < 4; ++j) vv[j] = T1s[row][k0 + c4 * 4 + j];
        union { half_t h[4]; uint2 u2; } H, L;
#pragma unroll
        for (int j = 0; j < 4; ++j) {
          half_t h = (half_t)vv[j];
          H.h[j] = h; L.h[j] = (half_t)(vv[j] - (float)h);
        }
        int s16 = row & 15;
        *(uint2*)(AHL + row * 256 + (((c4 >> 1) ^ s16) * 16) + (c4 & 1) * 8) = H.u2;
        *(uint2*)(AHL + row * 256 + ((((c4 >> 1) + 8) ^ s16) * 16) + (c4 & 1) * 8) = L.u2;
      }
    }
    {
#pragma unroll
      for (int p = 0; p < 8; ++p) {
        int f = t + p * 256;
        int row = f >> 3, h8 = f & 7;
        uint2 v = *(const uint2*)(WVT + (size_t)row * 256 + k0 + h8 * 8);
        uint2 v2 = *(const uint2*)(WVT + (size_t)row * 256 + k0 + h8 * 8 + 4);
        int slot = h8 ^ (row & 7);
        *(uint2*)(GHL + row * 128 + slot * 16) = v;
        *(uint2*)(GHL + row * 128 + slot * 16 + 8) = v2;
      }
    }
    __syncthreads();
#pragma unroll
    for (int kk = 0; kk < 4; ++kk) {
      int kb = kk * 32 + hi * 16;
      int arow = r31;
      int s16 = arow & 15;
      f16x8 Ah = *(const f16x8*)(AHL + arow * 256 + (((kb >> 4) ^ s16) * 16));
      f16x8 Al = *(const f16x8*)(AHL + arow * 256 + ((((kb >> 4) + 8) ^ s16) * 16));
#pragma unroll
      for (int n = 0; n < 2; ++n) {
        int row = w * 64 + n * 32 + r31;
        f16x8 Bf = *(const f16x8*)(GHL + row * 128 + (((kb >> 4) ^ (row & 7)) * 16));
        acc2[n] = __builtin_amdgcn_mfma_f32_32x32x16_f16(Ah, Bf, acc2[n], 0, 0, 0);
        acc2[n] = __builtin_amdgcn_mfma_f32_32x32x16_f16(Al, Bf, acc2[n], 0, 0, 0);
      }
    }
    __syncthreads();
  }
#pragma unroll
  for (int n = 0; n < 2; ++n)
#pragma unroll
    for (int r = 0; r < 16; ++r)
      T1s[(r & 3) + 8 * (r >> 2) + 4 * hi][w * 64 + n * 32 + r31] = acc2[n][r];
  __syncthreads();
  {  // pack S -> f16 [o][c]
    half_t* Sb = (half_t*)(ws + OFF_S16) + (size_t)b * 65536;
    int row = t >> 3, seg = t & 7;
#pragma unroll
    for (int u = 0; u < 4; ++u) {
      union { half_t h[8]; uint4 v; } P;
#pragma unroll
      for (int j = 0; j < 8; ++j)
        P.h[j] = (half_t)T1s[row][seg * 32 + u * 8 + j];
      *(uint4*)(Sb + (size_t)(r0 + row) * 256 + seg * 32 + u * 8) = P.v;
    }
  }
}

// ---------------- final: out = x + S[b] @ xn + const, f16 MFMA --------------
__global__ __launch_bounds__(256, 3) void final_mfma_k(
    const float* __restrict__ x, float* __restrict__ out,
    const float* __restrict__ ws) {
  __shared__ __align__(16) char Bt[16384];  // [64 n][256B] swizzled
  int b = blockIdx.y, n0 = blockIdx.x * 64;
  int t = threadIdx.x, lane = t & 63, w = t >> 6;
  int r31 = lane & 31, hi = lane >> 5;
  const half_t* Shb = (const half_t*)(ws + OFF_S16) + (size_t)b * 65536;
  const float* xb = x + (size_t)b * (C_ * (size_t)N_);
  const float* scb = ws + OFF_SC + b * 256;
  const float* shb = ws + OFF_SH + b * 256;
  f32x16 acc[2][2] = {};
  for (int c0 = 0; c0 < 256; c0 += 128) {
#pragma unroll
    for (int p = 0; p < 8; ++p) {
      int f = t + p * 256;
      int cl = f >> 4, j4 = f & 15;
      int c = c0 + cl;
      float4 v = *(const float4*)(xb + (size_t)c * N_ + n0 + j4 * 4);
      float sc = scb[c], sh = shb[c];
      float vv[4] = {v.x * sc + sh, v.y * sc + sh, v.z * sc + sh, v.w * sc + sh};
      int cb = cl * 2, b16 = cb & ~15, off = cb & 15;
#pragma unroll
      for (int e = 0; e < 4; ++e) {
        int nn = j4 * 4 + e;
        *(half_t*)(Bt + nn * 256 + (b16 ^ ((nn & 15) << 4)) + off) = (half_t)vv[e];
      }
    }
    __syncthreads();
#pragma unroll
    for (int kk = 0; kk < 8; ++kk) {
      int byte = kk * 32 + hi * 16;
      int cA = c0 + kk * 16 + hi * 8;
      f16x8 Af[2], Bf[2];
#pragma unroll
      for (int m = 0; m < 2; ++m) {
        int o = w * 64 + m * 32 + r31;
        Af[m] = *(const f16x8*)(Shb + (size_t)o * 256 + cA);
      }
#pragma unroll
      for (int n = 0; n < 2; ++n) {
        int nn = n * 32 + r31;
        Bf[n] = *(const f16x8*)(Bt + nn * 256 + (byte ^ ((nn & 15) << 4)));
      }
#pragma unroll
      for (int m = 0; m < 2; ++m)
#pragma unroll
        for (int n = 0; n < 2; ++n)
          acc[m][n] = __builtin_amdgcn_mfma_f32_32x32x16_f16(Af[m], Bf[n], acc[m][n], 0, 0, 0);
    }
    __syncthreads();
  }
  float* ob = out + (size_t)b * (C_ * (size_t)N_);
  const float* cstb = ws + OFF_CONST + b * 256;
#pragma unroll
  for (int m = 0; m < 2; ++m)
#pragma unroll
    for (int r = 0; r < 16; ++r) {
      int o = w * 64 + m * 32 + (r & 3) + 8 * (r >> 2) + 4 * hi;
      float cv = cstb[o];
      size_t base = (size_t)o * N_ + n0;
#pragma unroll
      for (int n = 0; n < 2; ++n) {
        int col = n * 32 + r31;
        ob[base + col] = acc[m][n][r] + xb[base + col] + cv;
      }
    }
}

extern "C" void kernel_launch(void* const* d_in, const int* in_sizes, int n_in,
                              void* d_out, int out_size, void* d_ws,
                              size_t ws_size, hipStream_t stream) {
  const float* x = (const float*)d_in[0];
  const float* gw = (const float*)d_in[1];
  const float* gb = (const float*)d_in[2];
  const float* qkvw = (const float*)d_in[3];
  const float* qkvb = (const float*)d_in[4];
  const float* pw = (const float*)d_in[5];
  const float* pb = (const float*)d_in[6];
  float* out = (float*)d_out;
  float* ws = (float*)d_ws;

  hipLaunchKernelGGL(gram_v4_k, dim3(256), dim3(512), 0, stream, x, ws);
  hipLaunchKernelGGL(prep_k, dim3(32), dim3(256), 0, stream, gw, gb, qkvw, ws);
  hipLaunchKernelGGL(gsum_k, dim3(2048), dim3(256), 0, stream, ws);
  hipLaunchKernelGGL(wvt_k, dim3(256), dim3(256), 0, stream, qkvw, ws);
  hipLaunchKernelGGL(fused_logits_k, dim3(8, 32), dim3(256), 0, stream, qkvw, qkvb, ws);
  hipLaunchKernelGGL(fused_s_k, dim3(8, 32), dim3(256), 0, stream, pw, pb, ws);
  hipLaunchKernelGGL(final_mfma_k, dim3(64, 32), dim3(256), 0, stream, x, out, ws);
}